// Round 1
// baseline (2141.000 us; speedup 1.0000x reference)
//
#include <hip/hip_runtime.h>

// LSTM with projection, fp32.
// B=4096, T=512, INPUT=4, HIDDEN=64, PROJ=52.
// Strategy: lane j <-> hidden unit j (c,d per-lane), lane p <-> proj unit p (h per-lane).
// All weights register-resident per lane (W_hh rows: 208 regs, W_hr row: 64 regs).
// Cross-lane broadcast via v_readlane (VALU) -> scalar operand of FMA. No LDS, no barriers.
// Each wave carries NB=4 batch elements; 4 waves/block; 256 blocks -> 16 batches/CU.

#define T_STEPS 512
#define HID 64
#define NPROJ 52
#define NB 4
#define WAVES_PER_BLOCK 4
#define BATCH_PER_BLOCK (NB * WAVES_PER_BLOCK)

__device__ __forceinline__ float rl(float v, int lane) {
    return __int_as_float(__builtin_amdgcn_readlane(__float_as_int(v), lane));
}

__device__ __forceinline__ float sigmoid_f(float x) {
    // 1 / (1 + exp(-x)); handles saturation via inf -> rcp(inf)=0
    return __builtin_amdgcn_rcpf(1.0f + __expf(-x));
}

__device__ __forceinline__ float tanh_f(float x) {
    // tanh(x) = 1 - 2/(exp(2x)+1); exp overflow -> inf -> 1 - 0 = 1 (correct saturation)
    return fmaf(-2.0f, __builtin_amdgcn_rcpf(1.0f + __expf(2.0f * x)), 1.0f);
}

__global__ __launch_bounds__(256, 1)
void lstmp_kernel(const float* __restrict__ x,      // [4096][512][4]
                  const float* __restrict__ Wih,    // [256][4]
                  const float* __restrict__ Whh,    // [256][52]
                  const float* __restrict__ bih,    // [256]
                  const float* __restrict__ bhh,    // [256]
                  const float* __restrict__ Whr,    // [52][64]
                  float* __restrict__ out)          // [4096][52]
{
    const int lane = threadIdx.x & 63;
    const int wave = threadIdx.x >> 6;
    const int b0 = blockIdx.x * BATCH_PER_BLOCK + wave * NB;

    // ---- register-cache weights (one-time, loop-invariant) ----
    float whh[4][NPROJ];   // 208 regs: this lane's 4 gate rows of W_hh
    float wih[4][4];       // 16
    float bias[4];         // 4
#pragma unroll
    for (int g = 0; g < 4; ++g) {
        const int row = g * HID + lane;
        const float4* wr = reinterpret_cast<const float4*>(Whh + row * NPROJ); // 208B rows, 16B aligned
#pragma unroll
        for (int q = 0; q < 13; ++q) {
            float4 v = wr[q];
            whh[g][q * 4 + 0] = v.x;
            whh[g][q * 4 + 1] = v.y;
            whh[g][q * 4 + 2] = v.z;
            whh[g][q * 4 + 3] = v.w;
        }
        float4 wi = reinterpret_cast<const float4*>(Wih)[row];
        wih[g][0] = wi.x; wih[g][1] = wi.y; wih[g][2] = wi.z; wih[g][3] = wi.w;
        bias[g] = bih[row] + bhh[row];
    }

    float whr[HID];        // 64 regs: W_hr row for proj unit p=lane (zeros for lanes >= 52)
    if (lane < NPROJ) {
        const float4* wr = reinterpret_cast<const float4*>(Whr + lane * HID); // 256B rows
#pragma unroll
        for (int q = 0; q < 16; ++q) {
            float4 v = wr[q];
            whr[q * 4 + 0] = v.x;
            whr[q * 4 + 1] = v.y;
            whr[q * 4 + 2] = v.z;
            whr[q * 4 + 3] = v.w;
        }
    } else {
#pragma unroll
        for (int q = 0; q < HID; ++q) whr[q] = 0.0f;
    }

    // ---- recurrent state ----
    float h[NB], c[NB];
#pragma unroll
    for (int n = 0; n < NB; ++n) { h[n] = 0.0f; c[n] = 0.0f; }

    const float4* xp = reinterpret_cast<const float4*>(x); // one float4 per (b, t)
    float4 xv[NB];
#pragma unroll
    for (int n = 0; n < NB; ++n) xv[n] = xp[(size_t)(b0 + n) * T_STEPS];

    for (int t = 0; t < T_STEPS; ++t) {
        // prefetch next timestep's x while computing this one (hides cold-miss latency)
        const int tn = (t + 1 < T_STEPS) ? (t + 1) : t;
        float4 xnext[NB];
#pragma unroll
        for (int n = 0; n < NB; ++n) xnext[n] = xp[(size_t)(b0 + n) * T_STEPS + tn];

        // gate pre-activations: bias + x @ W_ih^T
        float ai[NB], af[NB], ag[NB], ao[NB];
#pragma unroll
        for (int n = 0; n < NB; ++n) {
            ai[n] = fmaf(xv[n].w, wih[0][3], fmaf(xv[n].z, wih[0][2], fmaf(xv[n].y, wih[0][1], fmaf(xv[n].x, wih[0][0], bias[0]))));
            af[n] = fmaf(xv[n].w, wih[1][3], fmaf(xv[n].z, wih[1][2], fmaf(xv[n].y, wih[1][1], fmaf(xv[n].x, wih[1][0], bias[1]))));
            ag[n] = fmaf(xv[n].w, wih[2][3], fmaf(xv[n].z, wih[2][2], fmaf(xv[n].y, wih[2][1], fmaf(xv[n].x, wih[2][0], bias[2]))));
            ao[n] = fmaf(xv[n].w, wih[3][3], fmaf(xv[n].z, wih[3][2], fmaf(xv[n].y, wih[3][1], fmaf(xv[n].x, wih[3][0], bias[3]))));
        }

        // + h @ W_hh^T : h[n][k] broadcast from lane k via readlane, weights per-lane
#pragma unroll
        for (int k = 0; k < NPROJ; ++k) {
#pragma unroll
            for (int n = 0; n < NB; ++n) {
                const float hk = rl(h[n], k);
                ai[n] = fmaf(hk, whh[0][k], ai[n]);
                af[n] = fmaf(hk, whh[1][k], af[n]);
                ag[n] = fmaf(hk, whh[2][k], ag[n]);
                ao[n] = fmaf(hk, whh[3][k], ao[n]);
            }
        }

        // activations + cell update + d = o * tanh(c)   (lane = hidden unit)
        float d[NB];
#pragma unroll
        for (int n = 0; n < NB; ++n) {
            const float i_ = sigmoid_f(ai[n]);
            const float f_ = sigmoid_f(af[n]);
            const float g_ = tanh_f(ag[n]);
            const float o_ = sigmoid_f(ao[n]);
            const float cn = fmaf(f_, c[n], i_ * g_);
            c[n] = cn;
            d[n] = o_ * tanh_f(cn);
        }

        // projection: h_new[p] = sum_j W_hr[p][j] * d[j]   (lane = proj unit p)
        float hn[NB];
#pragma unroll
        for (int n = 0; n < NB; ++n) hn[n] = 0.0f;
#pragma unroll
        for (int jj = 0; jj < HID; ++jj) {
#pragma unroll
            for (int n = 0; n < NB; ++n) {
                const float dj = rl(d[n], jj);
                hn[n] = fmaf(dj, whr[jj], hn[n]);
            }
        }

#pragma unroll
        for (int n = 0; n < NB; ++n) { h[n] = hn[n]; xv[n] = xnext[n]; }
    }

    if (lane < NPROJ) {
#pragma unroll
        for (int n = 0; n < NB; ++n) out[(size_t)(b0 + n) * NPROJ + lane] = h[n];
    }
}

extern "C" void kernel_launch(void* const* d_in, const int* in_sizes, int n_in,
                              void* d_out, int out_size, void* d_ws, size_t ws_size,
                              hipStream_t stream) {
    const float* x   = (const float*)d_in[0];
    const float* Wih = (const float*)d_in[1];
    const float* Whh = (const float*)d_in[2];
    const float* bih = (const float*)d_in[3];
    const float* bhh = (const float*)d_in[4];
    const float* Whr = (const float*)d_in[5];
    float* out = (float*)d_out;

    const int batch = 4096;
    dim3 grid(batch / BATCH_PER_BLOCK);   // 256 blocks, 1 per CU
    dim3 block(WAVES_PER_BLOCK * 64);     // 4 waves
    lstmp_kernel<<<grid, block, 0, stream>>>(x, Wih, Whh, bih, bhh, Whr, out);
}

// Round 2
// 1067.552 us; speedup vs baseline: 2.0055x; 2.0055x over previous
//
#include <hip/hip_runtime.h>

// LSTMP fp32 I/O, fp16-packed weights + v_dot2_f32_f16 inner product.
// B=4096, T=512, IN=4, HID=64, PROJ=52.
// Wave owns NB=4 batch recurrences end-to-end. lane j = hidden unit (c,d),
// lane p = proj unit (h). Weights register-resident as packed f16 pairs:
//   whh2: 4 gates x 26 pairs = 104 VGPRs, whr2: 32, wih fp32: 16.
// Broadcast operands (h, d) are pair-packed across lanes once per step via
// ds_bpermute, then one v_readlane feeds each v_dot2 (SGPR operand).
// No LDS tiles, no barriers, no spills (live set ~200 < 256 arch VGPRs).

#define T_STEPS 512
#define HID 64
#define NPROJ 52
#define NB 4
#define WAVES_PER_BLOCK 4
#define BATCH_PER_BLOCK (NB * WAVES_PER_BLOCK)

typedef _Float16 h2 __attribute__((ext_vector_type(2)));

__device__ __forceinline__ int rl_i(int v, int lane) {
    return __builtin_amdgcn_readlane(v, lane);
}

// dot2: a.x*b.x + a.y*b.y + c (fp32 accumulate)
__device__ __forceinline__ float dot2(h2 a, h2 b, float c) {
#if __has_builtin(__builtin_amdgcn_fdot2)
    return __builtin_amdgcn_fdot2(a, b, c, false);
#else
    return fmaf((float)a.y, (float)b.y, fmaf((float)a.x, (float)b.x, c));
#endif
}

__device__ __forceinline__ h2 pack_lo16(int a, int b) {
    union { unsigned short s[2]; h2 v; } u;
    u.s[0] = (unsigned short)(a & 0xffff);
    u.s[1] = (unsigned short)(b & 0xffff);
    return u.v;
}

__device__ __forceinline__ int f32_to_f16_bits(float f) {
    _Float16 hv = (_Float16)f;
    return (int)__builtin_bit_cast(unsigned short, hv);
}

__device__ __forceinline__ float sigmoid_f(float x) {
    return __builtin_amdgcn_rcpf(1.0f + __expf(-x));
}

__device__ __forceinline__ float tanh_f(float x) {
    // 1 - 2/(exp(2x)+1); exp overflow -> inf -> rcp -> 0 -> 1 (correct saturation)
    return fmaf(-2.0f, __builtin_amdgcn_rcpf(1.0f + __expf(2.0f * x)), 1.0f);
}

__global__ __launch_bounds__(256, 1)
void lstmp_kernel(const float* __restrict__ x,      // [4096][512][4]
                  const float* __restrict__ Wih,    // [256][4]
                  const float* __restrict__ Whh,    // [256][52]
                  const float* __restrict__ bih,    // [256]
                  const float* __restrict__ bhh,    // [256]
                  const float* __restrict__ Whr,    // [52][64]
                  float* __restrict__ out)          // [4096][52]
{
    const int lane = threadIdx.x & 63;
    const int wave = threadIdx.x >> 6;
    const int b0 = blockIdx.x * BATCH_PER_BLOCK + wave * NB;

    // bpermute byte-addresses for pair packing: lane j gathers lanes 2j, 2j+1
    const int addrE = (((2 * lane) & 63) * 4);
    const int addrO = (((2 * lane + 1) & 63) * 4);

    // ---- register-cache weights as packed f16 pairs (one-time) ----
    h2 whh2[4][NPROJ / 2];   // 104 VGPRs
    float wih[4][4];         // 16 (x path stays fp32)
    float bias[4];           // 4
#pragma unroll
    for (int g = 0; g < 4; ++g) {
        const int row = g * HID + lane;
        const float* wr = Whh + row * NPROJ;
#pragma unroll
        for (int q = 0; q < NPROJ / 2; ++q) {
            whh2[g][q] = h2{(_Float16)wr[2 * q], (_Float16)wr[2 * q + 1]};
        }
        float4 wi = reinterpret_cast<const float4*>(Wih)[row];
        wih[g][0] = wi.x; wih[g][1] = wi.y; wih[g][2] = wi.z; wih[g][3] = wi.w;
        bias[g] = bih[row] + bhh[row];
    }

    h2 whr2[HID / 2];        // 32 VGPRs; zero for lanes >= 52
#pragma unroll
    for (int q = 0; q < HID / 2; ++q) whr2[q] = h2{(_Float16)0.0f, (_Float16)0.0f};
    if (lane < NPROJ) {
        const float* wr = Whr + lane * HID;
#pragma unroll
        for (int q = 0; q < HID / 2; ++q) {
            whr2[q] = h2{(_Float16)wr[2 * q], (_Float16)wr[2 * q + 1]};
        }
    }

    // ---- recurrent state ----
    float c[NB];
    int hpk[NB];             // lane j holds packed f16 pair (h[2j], h[2j+1])
#pragma unroll
    for (int n = 0; n < NB; ++n) { c[n] = 0.0f; hpk[n] = 0; }
    float hn[NB];            // fp32 h (lane p = proj unit), for final output
#pragma unroll
    for (int n = 0; n < NB; ++n) hn[n] = 0.0f;

    const float4* xp = reinterpret_cast<const float4*>(x); // one float4 per (b,t)
    float4 xv[NB];
#pragma unroll
    for (int n = 0; n < NB; ++n) xv[n] = xp[(size_t)(b0 + n) * T_STEPS];

#pragma unroll 1
    for (int t = 0; t < T_STEPS; ++t) {
        // prefetch next timestep's x
        const int tn = (t + 1 < T_STEPS) ? (t + 1) : t;
        float4 xnext[NB];
#pragma unroll
        for (int n = 0; n < NB; ++n) xnext[n] = xp[(size_t)(b0 + n) * T_STEPS + tn];

        // gate pre-activations: bias + x @ Wih^T (fp32 exact)
        float ai[NB], af[NB], ag[NB], ao[NB];
#pragma unroll
        for (int n = 0; n < NB; ++n) {
            ai[n] = fmaf(xv[n].w, wih[0][3], fmaf(xv[n].z, wih[0][2], fmaf(xv[n].y, wih[0][1], fmaf(xv[n].x, wih[0][0], bias[0]))));
            af[n] = fmaf(xv[n].w, wih[1][3], fmaf(xv[n].z, wih[1][2], fmaf(xv[n].y, wih[1][1], fmaf(xv[n].x, wih[1][0], bias[1]))));
            ag[n] = fmaf(xv[n].w, wih[2][3], fmaf(xv[n].z, wih[2][2], fmaf(xv[n].y, wih[2][1], fmaf(xv[n].x, wih[2][0], bias[2]))));
            ao[n] = fmaf(xv[n].w, wih[3][3], fmaf(xv[n].z, wih[3][2], fmaf(xv[n].y, wih[3][1], fmaf(xv[n].x, wih[3][0], bias[3]))));
        }

        // + h @ Whh^T: one readlane per (n, k-pair) feeds 4 dot2 (SGPR src)
#pragma unroll
        for (int q = 0; q < NPROJ / 2; ++q) {
#pragma unroll
            for (int n = 0; n < NB; ++n) {
                const h2 hq = __builtin_bit_cast(h2, rl_i(hpk[n], q));
                ai[n] = dot2(hq, whh2[0][q], ai[n]);
                af[n] = dot2(hq, whh2[1][q], af[n]);
                ag[n] = dot2(hq, whh2[2][q], ag[n]);
                ao[n] = dot2(hq, whh2[3][q], ao[n]);
            }
        }

        // activations + cell update; d -> f16, pair-pack via bpermute
        int dpk[NB];
#pragma unroll
        for (int n = 0; n < NB; ++n) {
            const float i_ = sigmoid_f(ai[n]);
            const float f_ = sigmoid_f(af[n]);
            const float g_ = tanh_f(ag[n]);
            const float o_ = sigmoid_f(ao[n]);
            const float cn = fmaf(f_, c[n], i_ * g_);
            c[n] = cn;
            const int dbits = f32_to_f16_bits(o_ * tanh_f(cn));
            dpk[n] = __builtin_bit_cast(int,
                pack_lo16(__builtin_amdgcn_ds_bpermute(addrE, dbits),
                          __builtin_amdgcn_ds_bpermute(addrO, dbits)));
        }

        // projection: h[p] = sum_j Whr[p][j] * d[j]; one readlane per (n, j-pair)
#pragma unroll
        for (int n = 0; n < NB; ++n) hn[n] = 0.0f;
#pragma unroll
        for (int jp = 0; jp < HID / 2; ++jp) {
#pragma unroll
            for (int n = 0; n < NB; ++n) {
                const h2 dj = __builtin_bit_cast(h2, rl_i(dpk[n], jp));
                hn[n] = dot2(dj, whr2[jp], hn[n]);
            }
        }

        // h -> f16, pair-pack for next step's gate broadcasts
#pragma unroll
        for (int n = 0; n < NB; ++n) {
            const int hbits = f32_to_f16_bits(hn[n]);
            hpk[n] = __builtin_bit_cast(int,
                pack_lo16(__builtin_amdgcn_ds_bpermute(addrE, hbits),
                          __builtin_amdgcn_ds_bpermute(addrO, hbits)));
            xv[n] = xnext[n];
        }
    }

    if (lane < NPROJ) {
#pragma unroll
        for (int n = 0; n < NB; ++n) out[(size_t)(b0 + n) * NPROJ + lane] = hn[n];
    }
}

extern "C" void kernel_launch(void* const* d_in, const int* in_sizes, int n_in,
                              void* d_out, int out_size, void* d_ws, size_t ws_size,
                              hipStream_t stream) {
    const float* x   = (const float*)d_in[0];
    const float* Wih = (const float*)d_in[1];
    const float* Whh = (const float*)d_in[2];
    const float* bih = (const float*)d_in[3];
    const float* bhh = (const float*)d_in[4];
    const float* Whr = (const float*)d_in[5];
    float* out = (float*)d_out;

    const int batch = 4096;
    dim3 grid(batch / BATCH_PER_BLOCK);   // 256 blocks, 1 per CU
    dim3 block(WAVES_PER_BLOCK * 64);     // 4 waves, 1 wave/SIMD
    lstmp_kernel<<<grid, block, 0, stream>>>(x, Wih, Whh, bih, bhh, Whr, out);
}

// Round 3
// 394.767 us; speedup vs baseline: 5.4235x; 2.7043x over previous
//
#include <hip/hip_runtime.h>

// LSTMP via MFMA, fp32 I/O, f16 compute with fp32 accumulate.
// B=4096, T=512, IN=4, HID=64, PROJ=52.
//
// Orientation: M = output unit (gate row / proj row), N = batch (16/block).
//   gates = [Whh | Wih | bias | 0pad] (256 x 64) @ [h; x; 1; 0] (64 x 16)
//   h'    = [Whr | 0pad]              ( 64 x 64) @ [d]          (64 x 16)
// A-operands are STATIC -> register-resident A-fragments (loaded once).
// Wave w owns gate tiles {w, w+4, w+8, w+12} = i,f,g,o for hid in [16w,16w+16)
//   -> cell update entirely per-lane (c[4]/lane). Projection: wave w owns
//   proj tile w. B-operands (h|x|1, d) round-trip through LDS each step
//   (rows padded to 136 B -> <=2-way bank conflicts on b64 reads = free).
// 2 barriers/step. MFMA frag layouts (16x16 family, guide-verified):
//   A[m=lane&15][k=quad*8+j], B[k=quad*8+j][n=lane&15], C[m=(quad)*4+reg][n=lane&15].

#define T_STEPS 512
#define HID 64
#define NPROJ 52
#define NBATCH 16          // batches per block; grid = 4096/16 = 256 blocks
#define ROWB 136           // LDS row stride bytes (64 f16 = 128B data + 8B pad)
#define ROWDW 34

typedef _Float16 half8 __attribute__((ext_vector_type(8)));
typedef float f32x4 __attribute__((ext_vector_type(4)));

__device__ __forceinline__ float sigmoid_f(float x) {
    return __builtin_amdgcn_rcpf(1.0f + __expf(-x));
}
__device__ __forceinline__ float tanh_f(float x) {
    // 1 - 2/(exp(2x)+1); overflow -> inf -> rcp -> 0 -> 1 (correct saturation)
    return fmaf(-2.0f, __builtin_amdgcn_rcpf(1.0f + __expf(2.0f * x)), 1.0f);
}
// RTNE f32->f16 pair pack (low = a)
__device__ __forceinline__ unsigned pk(float a, float b) {
    unsigned short la = __builtin_bit_cast(unsigned short, (_Float16)a);
    unsigned short lb = __builtin_bit_cast(unsigned short, (_Float16)b);
    return (unsigned)la | ((unsigned)lb << 16);
}

// B-fragment read: 8 consecutive f16 at row b, k = ch*32 + quad*8 .. +8
__device__ __forceinline__ half8 ldsB(const char* base, int b, int ch, int quad) {
    const char* p = base + b * ROWB + ch * 64 + quad * 16;
    union { unsigned long long q[2]; half8 h; } u;
    u.q[0] = *(const unsigned long long*)p;
    u.q[1] = *(const unsigned long long*)(p + 8);
    return u.h;
}

__global__ __launch_bounds__(256, 1)
void lstmp_kernel(const float* __restrict__ x,      // [4096][512][4]
                  const float* __restrict__ Wih,    // [256][4]
                  const float* __restrict__ Whh,    // [256][52]
                  const float* __restrict__ bih,    // [256]
                  const float* __restrict__ bhh,    // [256]
                  const float* __restrict__ Whr,    // [52][64]
                  float* __restrict__ out)          // [4096][52]
{
    __shared__ unsigned long long ldsbuf[(2 * NBATCH * ROWB) / 8];
    char* h_base = (char*)ldsbuf;                 // [16][136B]: k<52 h, 52-55 x, 56 = 1, 57-63 = 0
    char* d_base = h_base + NBATCH * ROWB;        // [16][136B]: d = o*tanh(c)

    const int lane = threadIdx.x & 63;
    const int wave = threadIdx.x >> 6;
    const int quad = lane >> 4;
    const int col  = lane & 15;                   // batch (B/C cols), row-in-tile (A)

    // ---- static A-fragments (one-time) ----
    // gates: wave w, gate g -> tile t = w + 4g -> rows = g*64 + (w*16 + col)
    half8 aG[4][2];
    const int hid = wave * 16 + col;
#pragma unroll
    for (int g = 0; g < 4; ++g) {
        const int row = g * HID + hid;
#pragma unroll
        for (int ch = 0; ch < 2; ++ch) {
#pragma unroll
            for (int j = 0; j < 8; ++j) {
                const int k = ch * 32 + quad * 8 + j;
                float v;
                if (k < NPROJ)      v = Whh[row * NPROJ + k];
                else if (k < 56)    v = Wih[row * 4 + (k - NPROJ)];
                else if (k == 56)   v = bih[row] + bhh[row];
                else                v = 0.0f;
                aG[g][ch][j] = (_Float16)v;
            }
        }
    }
    // projection: wave w -> proj rows w*16 + col (pad >= 52 with zeros)
    half8 aP[2];
    const int prow = wave * 16 + col;
#pragma unroll
    for (int ch = 0; ch < 2; ++ch) {
#pragma unroll
        for (int j = 0; j < 8; ++j) {
            const int k = ch * 32 + quad * 8 + j;
            aP[ch][j] = (_Float16)((prow < NPROJ) ? Whr[prow * HID + k] : 0.0f);
        }
    }

    // ---- init h_lds: h region (k<52 -> bytes 0..103) = 0 ----
    {
        unsigned* ldw = (unsigned*)ldsbuf;
        for (int i = threadIdx.x; i < NBATCH * 26; i += 256) {
            const int r = i / 26, cc = i % 26;
            ldw[r * ROWDW + cc] = 0u;
        }
    }
    // wave0/quad0: x(t=0) + constants (bytes 104..127), prefetch x(t=1)
    const float4* xp = (const float4*)x + (size_t)blockIdx.x * NBATCH * T_STEPS;
    float4 xreg = {0.0f, 0.0f, 0.0f, 0.0f};
    if (wave == 0 && quad == 0) {
        const float4 x0 = xp[(size_t)col * T_STEPS + 0];
        char* hp = h_base + col * ROWB;
        *(unsigned*)(hp + 104) = pk(x0.x, x0.y);
        *(unsigned*)(hp + 108) = pk(x0.z, x0.w);
        *(unsigned*)(hp + 112) = pk(1.0f, 0.0f);
        *(unsigned*)(hp + 116) = 0u;
        *(unsigned long long*)(hp + 120) = 0ull;
        xreg = xp[(size_t)col * T_STEPS + 1];
    }
    __syncthreads();

    // ---- recurrence ----
    float cacc[4] = {0.0f, 0.0f, 0.0f, 0.0f};   // c[hid = w*16 + quad*4 + r][batch = col]
    f32x4 accP = {0.0f, 0.0f, 0.0f, 0.0f};      // h'[p = w*16 + quad*4 + r][batch = col]

#pragma unroll 1
    for (int t = 0; t < T_STEPS; ++t) {
        // gates MFMA: [i,f,g,o for hid range] x 16 batches, K = 64
        const half8 b0 = ldsB(h_base, col, 0, quad);
        const half8 b1 = ldsB(h_base, col, 1, quad);
        f32x4 ai = {0.f,0.f,0.f,0.f}, af_ = {0.f,0.f,0.f,0.f};
        f32x4 ag_ = {0.f,0.f,0.f,0.f}, ao_ = {0.f,0.f,0.f,0.f};
        ai  = __builtin_amdgcn_mfma_f32_16x16x32_f16(aG[0][0], b0, ai,  0, 0, 0);
        af_ = __builtin_amdgcn_mfma_f32_16x16x32_f16(aG[1][0], b0, af_, 0, 0, 0);
        ag_ = __builtin_amdgcn_mfma_f32_16x16x32_f16(aG[2][0], b0, ag_, 0, 0, 0);
        ao_ = __builtin_amdgcn_mfma_f32_16x16x32_f16(aG[3][0], b0, ao_, 0, 0, 0);
        ai  = __builtin_amdgcn_mfma_f32_16x16x32_f16(aG[0][1], b1, ai,  0, 0, 0);
        af_ = __builtin_amdgcn_mfma_f32_16x16x32_f16(aG[1][1], b1, af_, 0, 0, 0);
        ag_ = __builtin_amdgcn_mfma_f32_16x16x32_f16(aG[2][1], b1, ag_, 0, 0, 0);
        ao_ = __builtin_amdgcn_mfma_f32_16x16x32_f16(aG[3][1], b1, ao_, 0, 0, 0);

        // activations + cell update (per-lane; hid = w*16 + quad*4 + r)
        float dv[4];
#pragma unroll
        for (int r = 0; r < 4; ++r) {
            const float iv = sigmoid_f(ai[r]);
            const float fv = sigmoid_f(af_[r]);
            const float gv = tanh_f(ag_[r]);
            const float ov = sigmoid_f(ao_[r]);
            const float cn = fmaf(fv, cacc[r], iv * gv);
            cacc[r] = cn;
            dv[r] = ov * tanh_f(cn);
        }

        // d -> LDS (f16 pairs; k = w*16 + quad*4 + {0..3} -> full 0..63 coverage)
        {
            char* p = d_base + col * ROWB + wave * 32 + quad * 8;
            const unsigned long long q =
                ((unsigned long long)pk(dv[2], dv[3]) << 32) | pk(dv[0], dv[1]);
            *(unsigned long long*)p = q;
        }
        __syncthreads();

        // projection MFMA: h' = Whr @ d, K = 64
        const half8 bd0 = ldsB(d_base, col, 0, quad);
        const half8 bd1 = ldsB(d_base, col, 1, quad);
        accP = (f32x4){0.f, 0.f, 0.f, 0.f};
        accP = __builtin_amdgcn_mfma_f32_16x16x32_f16(aP[0], bd0, accP, 0, 0, 0);
        accP = __builtin_amdgcn_mfma_f32_16x16x32_f16(aP[1], bd1, accP, 0, 0, 0);

        // h' -> LDS (only valid proj rows: waves 0-2 all, wave 3 quad 0 -> k 48..51)
        if (wave < 3 || quad == 0) {
            char* p = h_base + col * ROWB + wave * 32 + quad * 8;
            const unsigned long long q =
                ((unsigned long long)pk(accP[2], accP[3]) << 32) | pk(accP[0], accP[1]);
            *(unsigned long long*)p = q;
        }
        // x(t+1) -> LDS, prefetch x(t+2)
        if (wave == 0 && quad == 0) {
            char* hp = h_base + col * ROWB;
            *(unsigned*)(hp + 104) = pk(xreg.x, xreg.y);
            *(unsigned*)(hp + 108) = pk(xreg.z, xreg.w);
            const int tn = (t + 2 < T_STEPS) ? (t + 2) : (T_STEPS - 1);
            xreg = xp[(size_t)col * T_STEPS + tn];
        }
        __syncthreads();
    }

    // ---- epilogue: accP holds h_T (fp32) ----
    if (wave < 3 || quad == 0) {
        const size_t bg = (size_t)blockIdx.x * NBATCH + col;
        const int p0 = wave * 16 + quad * 4;
        float* o = out + bg * NPROJ + p0;
        o[0] = accP[0];
        o[1] = accP[1];
        o[2] = accP[2];
        o[3] = accP[3];
    }
}

extern "C" void kernel_launch(void* const* d_in, const int* in_sizes, int n_in,
                              void* d_out, int out_size, void* d_ws, size_t ws_size,
                              hipStream_t stream) {
    const float* x   = (const float*)d_in[0];
    const float* Wih = (const float*)d_in[1];
    const float* Whh = (const float*)d_in[2];
    const float* bih = (const float*)d_in[3];
    const float* bhh = (const float*)d_in[4];
    const float* Whr = (const float*)d_in[5];
    float* out = (float*)d_out;

    dim3 grid(4096 / NBATCH);   // 256 blocks, 1 per CU
    dim3 block(256);            // 4 waves
    lstmp_kernel<<<grid, block, 0, stream>>>(x, Wih, Whh, bih, bhh, Whr, out);
}

// Round 4
// 341.257 us; speedup vs baseline: 6.2739x; 1.1568x over previous
//
#include <hip/hip_runtime.h>

// LSTMP via MFMA, fp32 I/O, f16 compute, fp32 accumulate.
// B=4096, T=512, IN=4, HID=64, PROJ=52. Grid 256 x 256thr (4 waves), 16 batch/block.
//
// Round-4 structure: ONE barrier per step.
//  - gates = [Whh|Wih|b]*L-scaled (256x64) @ [h;x;1] (64x16): 8 MFMA/wave,
//    wave w owns gates for hid in [16w,16w+16) -> cell update per-lane.
//  - d exchange: the only LDS traffic, double-buffered (WAR-free), 1 barrier.
//  - projection computed REDUNDANTLY by every wave (8 MFMA, free at 10% MfmaUtil)
//    with row-PERMUTED A-fragments: tile tt delivers proj rows
//    p = (tt>>1)*32 + quad*8 + (tt&1)*4 + r  at C lane (quad,col) reg r,
//    which IS the gate B-frag layout (k = quad*8+j) -> h' never touches LDS.
//  - log2e folded into weights (i,f,o rows xL; g rows x2L; c kept as c'=2L*c)
//    so sigmoid/tanh use raw v_exp_f32 (exp2) with free negate modifier.

#define T_STEPS 512
#define HID 64
#define NPROJ 52
#define NBATCH 16
#define ROWB 136            // LDS d-row stride bytes (128B data + 8B pad)
#define LOG2E 1.44269504088896340736f

typedef _Float16 half8 __attribute__((ext_vector_type(8)));
typedef float f32x4 __attribute__((ext_vector_type(4)));

__device__ __forceinline__ float exp2_f(float x) {
#if __has_builtin(__builtin_amdgcn_exp2f)
    return __builtin_amdgcn_exp2f(x);
#else
    return exp2f(x);
#endif
}
__device__ __forceinline__ float rcp_f(float x) {
    return __builtin_amdgcn_rcpf(x);
}

__global__ __launch_bounds__(256, 1)
void lstmp_kernel(const float* __restrict__ x,      // [4096][512][4]
                  const float* __restrict__ Wih,    // [256][4]
                  const float* __restrict__ Whh,    // [256][52]
                  const float* __restrict__ bih,    // [256]
                  const float* __restrict__ bhh,    // [256]
                  const float* __restrict__ Whr,    // [52][64]
                  float* __restrict__ out)          // [4096][52]
{
    __shared__ unsigned long long dlds[2 * NBATCH * ROWB / 8]; // double-buffered d

    const int lane = threadIdx.x & 63;
    const int wave = threadIdx.x >> 6;
    const int quad = lane >> 4;
    const int col  = lane & 15;

    // ---- gate A-fragments, log2e-folded (one-time) ----
    // A[m=col][k=ch*32+quad*8+j]; rows hid = w*16+col per gate.
    half8 aG[4][2];
    const int hid = wave * 16 + col;
#pragma unroll
    for (int g = 0; g < 4; ++g) {
        const float scale = (g == 2) ? (2.0f * LOG2E) : LOG2E;  // g-gate: tanh needs exp(2x)
        const int row = g * HID + hid;
#pragma unroll
        for (int ch = 0; ch < 2; ++ch) {
#pragma unroll
            for (int j = 0; j < 8; ++j) {
                const int k = ch * 32 + quad * 8 + j;
                float v;
                if (k < NPROJ)      v = Whh[row * NPROJ + k];
                else if (k < 56)    v = Wih[row * 4 + (k - NPROJ)];
                else if (k == 56)   v = bih[row] + bhh[row];
                else                v = 0.0f;
                aG[g][ch][j] = (_Float16)(v * scale);
            }
        }
    }

    // ---- proj A-fragments, row-permuted tiles (one-time) ----
    // tile tt computes within-tile row m -> proj row p = (tt>>1)*32 + (m>>2)*8 + (tt&1)*4 + (m&3)
    half8 aP[4][2];
#pragma unroll
    for (int tt = 0; tt < 4; ++tt) {
        const int p = ((tt >> 1) * 32) + ((col >> 2) * 8) + ((tt & 1) * 4) + (col & 3);
#pragma unroll
        for (int ch = 0; ch < 2; ++ch) {
#pragma unroll
            for (int j = 0; j < 8; ++j) {
                const int k = ch * 32 + quad * 8 + j;
                aP[tt][ch][j] = (_Float16)((p < NPROJ) ? Whr[p * HID + k] : 0.0f);
            }
        }
    }

    // ---- x registers (col = batch; redundant across quads/waves, L1-served) ----
    const float4* xp = (const float4*)x + (size_t)blockIdx.x * NBATCH * T_STEPS;
    const float4 x0 = xp[(size_t)col * T_STEPS + 0];
    float4 xv = xp[(size_t)col * T_STEPS + 1];   // holds x(t+1) during iteration t

    // ---- initial gate B-frags (t=0): h=0, x(0), bias-one ----
    half8 b0, b1;
#pragma unroll
    for (int j = 0; j < 8; ++j) { b0[j] = (_Float16)0.0f; b1[j] = (_Float16)0.0f; }
    if (quad == 2) {             // k=52..55 = x
        b1[4] = (_Float16)x0.x; b1[5] = (_Float16)x0.y;
        b1[6] = (_Float16)x0.z; b1[7] = (_Float16)x0.w;
    }
    if (quad == 3) {             // k=56 = 1.0 (bias column)
        b1[0] = (_Float16)1.0f;
    }

    float cacc[4] = {0.0f, 0.0f, 0.0f, 0.0f};   // c' = 2L*c, hid = w*16+quad*4+r
    f32x4 hp[4];                                 // proj C-results (permuted layout)

    const int dwoff = col * ROWB + wave * 32 + quad * 8;  // d write byte offset
    const int drbase = col * ROWB + quad * 16;            // d read base (ch*64 added)

#pragma unroll 1
    for (int t = 0; t < T_STEPS; ++t) {
        // ---- gates: 8 MFMA, K=64 ----
        f32x4 ai = {0.f,0.f,0.f,0.f}, af_ = {0.f,0.f,0.f,0.f};
        f32x4 ag_ = {0.f,0.f,0.f,0.f}, ao_ = {0.f,0.f,0.f,0.f};
        ai  = __builtin_amdgcn_mfma_f32_16x16x32_f16(aG[0][0], b0, ai,  0, 0, 0);
        af_ = __builtin_amdgcn_mfma_f32_16x16x32_f16(aG[1][0], b0, af_, 0, 0, 0);
        ag_ = __builtin_amdgcn_mfma_f32_16x16x32_f16(aG[2][0], b0, ag_, 0, 0, 0);
        ao_ = __builtin_amdgcn_mfma_f32_16x16x32_f16(aG[3][0], b0, ao_, 0, 0, 0);
        ai  = __builtin_amdgcn_mfma_f32_16x16x32_f16(aG[0][1], b1, ai,  0, 0, 0);
        af_ = __builtin_amdgcn_mfma_f32_16x16x32_f16(aG[1][1], b1, af_, 0, 0, 0);
        ag_ = __builtin_amdgcn_mfma_f32_16x16x32_f16(aG[2][1], b1, ag_, 0, 0, 0);
        ao_ = __builtin_amdgcn_mfma_f32_16x16x32_f16(aG[3][1], b1, ao_, 0, 0, 0);

        // ---- activations (pre-acts already scaled by L / 2L) ----
        char* dbuf = (char*)dlds + (t & 1) * (NBATCH * ROWB);
        union { _Float16 h[4]; unsigned long long q; } du;
#pragma unroll
        for (int r = 0; r < 4; ++r) {
            const float iv = rcp_f(1.0f + exp2_f(-ai[r]));                       // sigmoid
            const float fv = rcp_f(1.0f + exp2_f(-af_[r]));
            const float ov = rcp_f(1.0f + exp2_f(-ao_[r]));
            const float gs = fmaf(-4.0f * LOG2E, rcp_f(1.0f + exp2_f(ag_[r])),
                                  2.0f * LOG2E);                                 // 2L*tanh(g)
            const float cn = fmaf(fv, cacc[r], iv * gs);                         // c' = 2L*c
            cacc[r] = cn;
            const float th = fmaf(-2.0f, rcp_f(1.0f + exp2_f(cn)), 1.0f);        // tanh(c)
            du.h[r] = (_Float16)(ov * th);                                       // RTNE
        }
        *(unsigned long long*)(dbuf + dwoff) = du.q;   // hid = w*16+quad*4+{0..3}
        __syncthreads();                               // the ONLY barrier per step

        // ---- d B-frags from LDS ----
        half8 bd0, bd1;
        {
            const char* p0 = dbuf + drbase;
            union { unsigned long long q[2]; half8 h; } u0, u1;
            u0.q[0] = *(const unsigned long long*)(p0);
            u0.q[1] = *(const unsigned long long*)(p0 + 8);
            u1.q[0] = *(const unsigned long long*)(p0 + 64);
            u1.q[1] = *(const unsigned long long*)(p0 + 72);
            bd0 = u0.h; bd1 = u1.h;
        }

        // ---- projection: 8 MFMA, redundant per wave, permuted tiles ----
#pragma unroll
        for (int tt = 0; tt < 4; ++tt) {
            f32x4 acc = {0.f, 0.f, 0.f, 0.f};
            acc = __builtin_amdgcn_mfma_f32_16x16x32_f16(aP[tt][0], bd0, acc, 0, 0, 0);
            acc = __builtin_amdgcn_mfma_f32_16x16x32_f16(aP[tt][1], bd1, acc, 0, 0, 0);
            hp[tt] = acc;
        }

        // ---- build next-step gate B-frags in-register (h' = permuted C layout) ----
#pragma unroll
        for (int j = 0; j < 4; ++j) {
            b0[j]     = (_Float16)hp[0][j];   // k = quad*8 + j
            b0[4 + j] = (_Float16)hp[1][j];   // k = quad*8 + 4 + j
            b1[j]     = (_Float16)hp[2][j];   // k = 32 + quad*8 + j
            b1[4 + j] = (_Float16)hp[3][j];   // k = 32 + quad*8 + 4 + j
        }
        if (quad == 2) {                      // k=52..55 <- x(t+1)  (A rows 52..55 zeroed)
            b1[4] = (_Float16)xv.x; b1[5] = (_Float16)xv.y;
            b1[6] = (_Float16)xv.z; b1[7] = (_Float16)xv.w;
        }
        if (quad == 3) {                      // k=56 <- 1.0 (rest stay 0: A rows 56..63 zeroed)
            b1[0] = (_Float16)1.0f;
        }

        // prefetch x(t+2)
        const int tn = (t + 2 < T_STEPS) ? (t + 2) : (T_STEPS - 1);
        xv = xp[(size_t)col * T_STEPS + tn];
    }

    // ---- epilogue: every wave holds full h_T (fp32, permuted C layout); wave 0 writes ----
    if (wave == 0) {
        const size_t bg = (size_t)blockIdx.x * NBATCH + col;
        float* o = out + bg * NPROJ;
#pragma unroll
        for (int tt = 0; tt < 4; ++tt) {
            const int pb = ((tt >> 1) * 32) + (quad * 8) + ((tt & 1) * 4);
#pragma unroll
            for (int r = 0; r < 4; ++r) {
                const int p = pb + r;
                if (p < NPROJ) o[p] = hp[tt][r];
            }
        }
    }
}

extern "C" void kernel_launch(void* const* d_in, const int* in_sizes, int n_in,
                              void* d_out, int out_size, void* d_ws, size_t ws_size,
                              hipStream_t stream) {
    const float* x   = (const float*)d_in[0];
    const float* Wih = (const float*)d_in[1];
    const float* Whh = (const float*)d_in[2];
    const float* bih = (const float*)d_in[3];
    const float* bhh = (const float*)d_in[4];
    const float* Whr = (const float*)d_in[5];
    float* out = (float*)d_out;

    dim3 grid(4096 / NBATCH);   // 256 blocks, 1 per CU
    dim3 block(256);            // 4 waves
    lstmp_kernel<<<grid, block, 0, stream>>>(x, Wih, Whh, bih, bhh, Whr, out);
}